// Round 2
// baseline (227.649 us; speedup 1.0000x reference)
//
#include <hip/hip_runtime.h>

#define N_POS   65536
#define K_CODES 1024

// ws layout (bytes)
#define WS_LOSS   0
#define WS_ENORMF 64
#define WS_IDX    4224
#define WS_PB1    266368
#define WS_PK1    1314944

// numpy pairwise sum (n=64, contiguous branch): 8 accumulators, strided,
// combined ((r0+r1)+(r2+r3))+((r4+r5)+(r6+r7)). All ops explicitly rounded
// (no FMA contraction) to match numpy's elementwise square + pairwise add.
__device__ __forceinline__ float np_pairwise_sumsq64(const float* a) {
    float r[8];
    #pragma unroll
    for (int j = 0; j < 8; ++j) r[j] = __fmul_rn(a[j], a[j]);
    #pragma unroll
    for (int i = 8; i < 64; i += 8)
        #pragma unroll
        for (int j = 0; j < 8; ++j)
            r[j] = __fadd_rn(r[j], __fmul_rn(a[i + j], a[i + j]));
    return __fadd_rn(
        __fadd_rn(__fadd_rn(r[0], r[1]), __fadd_rn(r[2], r[3])),
        __fadd_rn(__fadd_rn(r[4], r[5]), __fadd_rn(r[6], r[7])));
}

// K1: enorm_f[k] = np.sum(emb*emb, axis=1) in fp32 numpy-pairwise order.
__global__ __launch_bounds__(256) void prep_kernel(
    const float* __restrict__ emb, float* __restrict__ enorm_f,
    float* __restrict__ loss)
{
    int k = blockIdx.x * 256 + threadIdx.x;
    if (k == 0) *loss = 0.0f;
    if (k < K_CODES) {
        float e[64];
        #pragma unroll
        for (int l = 0; l < 64; ++l) e[l] = emb[k * 64 + l];
        enorm_f[k] = np_pairwise_sumsq64(e);
    }
}

// K2: fp32 partial argmin replicating numpy semantics exactly.
// blockIdx = (group<<2)|split; block = 512 positions x 256 codes.
// score = round(znorm + enorm_k) - 2*dot_k, dot = sequential fma (sgemm order).
__global__ __launch_bounds__(256) void argmin_partial_kernel(
    const float* __restrict__ ze, const float* __restrict__ emb,
    const float* __restrict__ enorm_f,
    float* __restrict__ pb1, int* __restrict__ pk1)
{
    __shared__ __align__(16) float e_lds[64 * 64];
    __shared__ float en_lds[64];
    const int t = threadIdx.x;
    const int g = blockIdx.x >> 2;
    const int s = blockIdx.x & 3;
    const int n0 = g * 512 + t;
    const int n1 = n0 + 256;
    const float* z0p = ze + ((n0 >> 12) * 262144 + (n0 & 4095));
    const float* z1p = ze + ((n1 >> 12) * 262144 + (n1 & 4095));
    float za[64], zb[64];
    #pragma unroll
    for (int l = 0; l < 64; ++l) { za[l] = z0p[l * 4096]; zb[l] = z1p[l * 4096]; }

    const float zna = np_pairwise_sumsq64(za);
    const float znb = np_pairwise_sumsq64(zb);

    float b1a = 1e30f, b1b = 1e30f;
    int k1a = 0, k1b = 0;
    const int kbase = s * 256;

    for (int tile = 0; tile < 4; ++tile) {
        if (tile) __syncthreads();
        const float4* src = (const float4*)(emb + (kbase + tile * 64) * 64);
        float4* dst = (float4*)e_lds;
        #pragma unroll
        for (int j = 0; j < 4; ++j) dst[t + j * 256] = src[t + j * 256];
        if (t < 64) en_lds[t] = enorm_f[kbase + tile * 64 + t];
        __syncthreads();

        #pragma unroll 2
        for (int c = 0; c < 64; c += 2) {
            const float4* e0 = (const float4*)(e_lds + c * 64);
            const float4* e1 = (const float4*)(e_lds + c * 64 + 64);
            float a00 = 0.f, a01 = 0.f, a10 = 0.f, a11 = 0.f;
            #pragma unroll
            for (int q = 0; q < 16; ++q) {
                float4 p = e0[q];
                float4 r = e1[q];
                a00 = fmaf(za[4*q+0], p.x, a00); a01 = fmaf(zb[4*q+0], p.x, a01);
                a10 = fmaf(za[4*q+0], r.x, a10); a11 = fmaf(zb[4*q+0], r.x, a11);
                a00 = fmaf(za[4*q+1], p.y, a00); a01 = fmaf(zb[4*q+1], p.y, a01);
                a10 = fmaf(za[4*q+1], r.y, a10); a11 = fmaf(zb[4*q+1], r.y, a11);
                a00 = fmaf(za[4*q+2], p.z, a00); a01 = fmaf(zb[4*q+2], p.z, a01);
                a10 = fmaf(za[4*q+2], r.z, a10); a11 = fmaf(zb[4*q+2], r.z, a11);
                a00 = fmaf(za[4*q+3], p.w, a00); a01 = fmaf(zb[4*q+3], p.w, a01);
                a10 = fmaf(za[4*q+3], r.w, a10); a11 = fmaf(zb[4*q+3], r.w, a11);
            }
            int k0 = kbase + tile * 64 + c;
            // v = round(znorm + enorm); s = round(v - 2*dot)  [2*dot exact]
            float v0a = __fadd_rn(zna, en_lds[c]);
            float v1a = __fadd_rn(zna, en_lds[c + 1]);
            float v0b = __fadd_rn(znb, en_lds[c]);
            float v1b = __fadd_rn(znb, en_lds[c + 1]);
            float s0 = __fsub_rn(v0a, __fmul_rn(2.0f, a00));  // pos a, k0
            float s1 = __fsub_rn(v1a, __fmul_rn(2.0f, a10));  // pos a, k0+1
            float u0 = __fsub_rn(v0b, __fmul_rn(2.0f, a01));  // pos b, k0
            float u1 = __fsub_rn(v1b, __fmul_rn(2.0f, a11));  // pos b, k0+1
            if (s0 < b1a) { b1a = s0; k1a = k0;     }
            if (s1 < b1a) { b1a = s1; k1a = k0 + 1; }
            if (u0 < b1b) { b1b = u0; k1b = k0;     }
            if (u1 < b1b) { b1b = u1; k1b = k0 + 1; }
        }
    }
    pb1[s * N_POS + n0] = b1a; pk1[s * N_POS + n0] = k1a;
    pb1[s * N_POS + n1] = b1b; pk1[s * N_POS + n1] = k1b;
}

// K3: merge 4 K-splits; ascending split + strict < == numpy first-occurrence.
__global__ __launch_bounds__(256) void merge_kernel(
    const float* __restrict__ pb1, const int* __restrict__ pk1,
    int* __restrict__ idx_ws)
{
    int n = blockIdx.x * 256 + threadIdx.x;
    float B1 = pb1[n]; int K1 = pk1[n];
    #pragma unroll
    for (int s = 1; s < 4; ++s) {
        float v = pb1[s * N_POS + n]; int k = pk1[s * N_POS + n];
        if (v < B1) { B1 = v; K1 = k; }
    }
    idx_ws[n] = K1;
}

// K4: gather z_q, write idx as float, accumulate loss sum.
__global__ __launch_bounds__(256) void epilogue_kernel(
    const float* __restrict__ ze, const float* __restrict__ emb,
    const int* __restrict__ idx_ws,
    float* __restrict__ out_zq, float* __restrict__ out_idxf,
    float* __restrict__ loss)
{
    const int t = threadIdx.x;
    const int n = blockIdx.x * 256 + t;
    const int k = idx_ws[n];
    const int base = (n >> 12) * 262144 + (n & 4095);
    const float* epk = emb + k * 64;
    float lsum = 0.0f;
    #pragma unroll 8
    for (int l = 0; l < 64; ++l) {
        float q = epk[l];
        float z = ze[base + l * 4096];
        out_zq[base + l * 4096] = q;
        float d = q - z;
        lsum = fmaf(d, d, lsum);
    }
    out_idxf[n] = (float)k;
    #pragma unroll
    for (int off = 32; off > 0; off >>= 1) lsum += __shfl_down(lsum, off, 64);
    if ((t & 63) == 0) atomicAdd(loss, lsum);
}

// K5: loss = 1.25 * mean(diff^2)
__global__ void finalize_kernel(const float* __restrict__ loss, float* __restrict__ out_loss)
{
    *out_loss = 1.25f * (*loss) / 4194304.0f;
}

extern "C" void kernel_launch(void* const* d_in, const int* in_sizes, int n_in,
                              void* d_out, int out_size, void* d_ws, size_t ws_size,
                              hipStream_t stream)
{
    const float* ze  = (const float*)d_in[0];   // (16,64,64,64) fp32
    const float* emb = (const float*)d_in[1];   // (1024,64) fp32
    float* out = (float*)d_out;
    float* out_zq   = out;                // 4194304
    float* out_loss = out + 4194304;      // 1
    float* out_idxf = out + 4194305;      // 65536

    char* w = (char*)d_ws;
    float* ws_loss = (float*)(w + WS_LOSS);
    float* enorm_f = (float*)(w + WS_ENORMF);
    int*   idx_ws  = (int*)(w + WS_IDX);
    float* pb1     = (float*)(w + WS_PB1);
    int*   pk1     = (int*)(w + WS_PK1);

    prep_kernel<<<4, 256, 0, stream>>>(emb, enorm_f, ws_loss);
    argmin_partial_kernel<<<512, 256, 0, stream>>>(ze, emb, enorm_f, pb1, pk1);
    merge_kernel<<<256, 256, 0, stream>>>(pb1, pk1, idx_ws);
    epilogue_kernel<<<256, 256, 0, stream>>>(ze, emb, idx_ws, out_zq, out_idxf, ws_loss);
    finalize_kernel<<<1, 1, 0, stream>>>(ws_loss, out_loss);
}

// Round 3
// 164.606 us; speedup vs baseline: 1.3830x; 1.3830x over previous
//
#include <hip/hip_runtime.h>

typedef short bf16x8 __attribute__((ext_vector_type(8)));
typedef float f32x4  __attribute__((ext_vector_type(4)));

#define N_POS 65536
#define KC    1024
#define CAP   1024

// ws layout (bytes)
#define WS_LOSS  0
#define WS_ENORM 256
#define WS_EBF   4608   // 1024*64 bf16 (permuted) = 131072 B

__device__ __forceinline__ unsigned short f2bf(float f) {
    unsigned u = __float_as_uint(f);
    return (unsigned short)((u + 0x7fffu + ((u >> 16) & 1u)) >> 16);  // RTNE
}

// numpy pairwise sum (n=64): 8 accumulators, ((r0+r1)+(r2+r3))+((r4+r5)+(r6+r7)).
__device__ __forceinline__ float np_pairwise_sumsq64(const float* a) {
    float r[8];
    #pragma unroll
    for (int j = 0; j < 8; ++j) r[j] = __fmul_rn(a[j], a[j]);
    #pragma unroll
    for (int i = 8; i < 64; i += 8)
        #pragma unroll
        for (int j = 0; j < 8; ++j)
            r[j] = __fadd_rn(r[j], __fmul_rn(a[i + j], a[i + j]));
    return __fadd_rn(
        __fadd_rn(__fadd_rn(r[0], r[1]), __fadd_rn(r[2], r[3])),
        __fadd_rn(__fadd_rn(r[4], r[5]), __fadd_rn(r[6], r[7])));
}

// K1: enorm (numpy-exact) + bf16 codebook in MFMA-B-fragment-permuted layout:
// ebf[tile(64)][chunk j(8)][row r(16)][8 bf16], code = tile*16+r, dims 8j..8j+7.
__global__ __launch_bounds__(256) void prep_kernel(
    const float* __restrict__ emb, float* __restrict__ enorm,
    unsigned short* __restrict__ ebf, float* __restrict__ loss)
{
    int k = blockIdx.x * 256 + threadIdx.x;
    if (k == 0) *loss = 0.0f;
    if (k < KC) {
        float e[64];
        #pragma unroll
        for (int l = 0; l < 64; ++l) e[l] = emb[k * 64 + l];
        enorm[k] = np_pairwise_sumsq64(e);
        int tile = k >> 4, r = k & 15;
        #pragma unroll
        for (int j = 0; j < 8; ++j) {
            bf16x8 v;
            #pragma unroll
            for (int m = 0; m < 8; ++m) v[m] = (short)f2bf(e[j * 8 + m]);
            *(bf16x8*)(ebf + tile * 1024 + j * 128 + r * 8) = v;
        }
    }
}

// K2: fused VQ. Block = 128 positions, 4 waves x 32 pos. bf16 MFMA filter
// (pass1 row-min, pass2 candidate collect), exact fp32 numpy rescore of
// candidates, lex-(score,k) select, fused z_q gather + loss.
__global__ __launch_bounds__(256) void vq_kernel(
    const float* __restrict__ ze, const float* __restrict__ emb,
    const float* __restrict__ enormg, const unsigned short* __restrict__ ebf,
    float* __restrict__ out_zq, float* __restrict__ out_idxf,
    float* __restrict__ loss)
{
    __shared__ unsigned short zbf[128 * 64];   // 16384 B
    __shared__ float zf[128 * 65];             // 33280 B (pad +1: bank-spread)
    __shared__ float en_l[1024];               // 4096 B
    __shared__ float znorm_l[128], marg_l[128];
    __shared__ int kch[128];
    __shared__ unsigned cand[CAP];             // 4096 B  (pos<<16 | code)
    __shared__ float cscore[CAP];              // 4096 B
    __shared__ int lcnt;

    const int t = threadIdx.x;
    const int n0 = blockIdx.x * 128;
    const int gbase = (n0 >> 12) * 262144 + (n0 & 4095);
    if (t == 0) lcnt = 0;
    #pragma unroll
    for (int i = t; i < 1024; i += 256) en_l[i] = enormg[i];

    // stage z (fp32 + bf16): thread t -> pos p = t&127, dims half (t>>7)*32
    {
        const int p = t & 127, l0 = (t >> 7) * 32;
        #pragma unroll 8
        for (int j = 0; j < 32; ++j) {
            int l = l0 + j;
            float v = ze[gbase + p + l * 4096];
            zf[p * 65 + l] = v;
            zbf[p * 64 + l] = f2bf(v);
        }
    }
    __syncthreads();

    // znorm (numpy pairwise, exact) + margin = 1.67e-5*sum|z| + 5e-5
    if (t < 128) {
        float a[64];
        #pragma unroll
        for (int l = 0; l < 64; ++l) a[l] = zf[t * 65 + l];
        znorm_l[t] = np_pairwise_sumsq64(a);
        float S = 0.0f;
        #pragma unroll
        for (int l = 0; l < 64; ++l) S += fabsf(a[l]);
        marg_l[t] = 1.67e-5f * S + 5e-5f;
    }
    __syncthreads();

    const int wv = t >> 6;
    const int lane = t & 63;
    const int r = lane & 15;   // B col (code-in-tile) == A row selector
    const int q = lane >> 4;   // quad
    const int wp = wv * 32;    // wave's first position

    // A-fragments (A[m=lane&15][k=quad*8+j]), two 16-pos sets, K=64 in 2 steps
    bf16x8 a00 = *(bf16x8*)&zbf[(wp + r) * 64 + q * 8];
    bf16x8 a01 = *(bf16x8*)&zbf[(wp + r) * 64 + 32 + q * 8];
    bf16x8 a10 = *(bf16x8*)&zbf[(wp + 16 + r) * 64 + q * 8];
    bf16x8 a11 = *(bf16x8*)&zbf[(wp + 16 + r) * 64 + 32 + q * 8];
    const unsigned short* bptr = ebf + q * 128 + r * 8;

    // ---- pass 1: per-row min over all 1024 codes ----
    float rm[8];
    #pragma unroll
    for (int i = 0; i < 8; ++i) rm[i] = 1e30f;
    #pragma unroll 4
    for (int tile = 0; tile < 64; ++tile) {
        bf16x8 b0 = *(const bf16x8*)(bptr + tile * 1024);
        bf16x8 b1 = *(const bf16x8*)(bptr + tile * 1024 + 512);
        f32x4 c0 = {0.f, 0.f, 0.f, 0.f}, c1 = {0.f, 0.f, 0.f, 0.f};
        c0 = __builtin_amdgcn_mfma_f32_16x16x32_bf16(a00, b0, c0, 0, 0, 0);
        c0 = __builtin_amdgcn_mfma_f32_16x16x32_bf16(a01, b1, c0, 0, 0, 0);
        c1 = __builtin_amdgcn_mfma_f32_16x16x32_bf16(a10, b0, c1, 0, 0, 0);
        c1 = __builtin_amdgcn_mfma_f32_16x16x32_bf16(a11, b1, c1, 0, 0, 0);
        float en = en_l[tile * 16 + r];
        #pragma unroll
        for (int i = 0; i < 4; ++i) {
            rm[i]     = fminf(rm[i],     fmaf(c0[i], -2.0f, en));
            rm[4 + i] = fminf(rm[4 + i], fmaf(c1[i], -2.0f, en));
        }
    }
    float thr[8];
    #pragma unroll
    for (int i = 0; i < 8; ++i) {
        float v = rm[i];
        v = fminf(v, __shfl_xor(v, 1, 16));
        v = fminf(v, __shfl_xor(v, 2, 16));
        v = fminf(v, __shfl_xor(v, 4, 16));
        v = fminf(v, __shfl_xor(v, 8, 16));
        int row = wp + ((i >= 4) ? 16 : 0) + q * 4 + (i & 3);
        thr[i] = v + marg_l[row];
    }

    // ---- pass 2: collect candidates (score <= rowmin + margin) ----
    #pragma unroll 4
    for (int tile = 0; tile < 64; ++tile) {
        bf16x8 b0 = *(const bf16x8*)(bptr + tile * 1024);
        bf16x8 b1 = *(const bf16x8*)(bptr + tile * 1024 + 512);
        f32x4 c0 = {0.f, 0.f, 0.f, 0.f}, c1 = {0.f, 0.f, 0.f, 0.f};
        c0 = __builtin_amdgcn_mfma_f32_16x16x32_bf16(a00, b0, c0, 0, 0, 0);
        c0 = __builtin_amdgcn_mfma_f32_16x16x32_bf16(a01, b1, c0, 0, 0, 0);
        c1 = __builtin_amdgcn_mfma_f32_16x16x32_bf16(a10, b0, c1, 0, 0, 0);
        c1 = __builtin_amdgcn_mfma_f32_16x16x32_bf16(a11, b1, c1, 0, 0, 0);
        float en = en_l[tile * 16 + r];
        int code = tile * 16 + r;
        #pragma unroll
        for (int i = 0; i < 4; ++i) {
            if (fmaf(c0[i], -2.0f, en) <= thr[i]) {
                int ci = atomicAdd(&lcnt, 1);
                if (ci < CAP) cand[ci] = ((unsigned)(wp + q * 4 + i) << 16) | code;
            }
            if (fmaf(c1[i], -2.0f, en) <= thr[4 + i]) {
                int ci = atomicAdd(&lcnt, 1);
                if (ci < CAP) cand[ci] = ((unsigned)(wp + 16 + q * 4 + i) << 16) | code;
            }
        }
    }
    __syncthreads();

    // ---- exact fp32 numpy rescore (bit-identical to the R2-verified path) ----
    int cnt = lcnt; if (cnt > CAP) cnt = CAP;
    for (int i = t; i < cnt; i += 256) {
        unsigned e = cand[i];
        int p = e >> 16, k = e & 0xffff;
        const float* ep = emb + k * 64;
        const float* zp = &zf[p * 65];
        float acc = 0.0f;
        #pragma unroll
        for (int l = 0; l < 64; ++l) acc = fmaf(zp[l], ep[l], acc);  // sgemm order
        float v = __fadd_rn(znorm_l[p], en_l[k]);
        cscore[i] = __fsub_rn(v, __fmul_rn(2.0f, acc));
    }
    __syncthreads();

    // ---- select: lexicographic (score, k) min == numpy first occurrence ----
    if (t < 128) {
        float best = 1e30f; int bk = 1 << 20;
        for (int i = 0; i < cnt; ++i) {
            unsigned e = cand[i];
            if ((int)(e >> 16) == t) {
                int k = e & 0xffff; float sc = cscore[i];
                if (sc < best || (sc == best && k < bk)) { best = sc; bk = k; }
            }
        }
        kch[t] = bk;
        out_idxf[n0 + t] = (float)bk;
    }
    __syncthreads();

    // ---- fused epilogue: z_q gather + loss partial ----
    {
        const int p = t & 127, l0 = (t >> 7) * 32;
        const int k = kch[p];
        const float* ep = emb + k * 64;
        float ls = 0.0f;
        #pragma unroll 8
        for (int j = 0; j < 32; ++j) {
            int l = l0 + j;
            float qv = ep[l];
            float zv = zf[p * 65 + l];
            out_zq[gbase + p + l * 4096] = qv;
            float d = qv - zv;
            ls = fmaf(d, d, ls);
        }
        #pragma unroll
        for (int off = 32; off > 0; off >>= 1) ls += __shfl_down(ls, off, 64);
        if (lane == 0) atomicAdd(loss, ls);
    }
}

// K3: loss = 1.25 * mean(diff^2)
__global__ void finalize_kernel(const float* __restrict__ loss, float* __restrict__ out_loss)
{
    *out_loss = 1.25f * (*loss) / 4194304.0f;
}

extern "C" void kernel_launch(void* const* d_in, const int* in_sizes, int n_in,
                              void* d_out, int out_size, void* d_ws, size_t ws_size,
                              hipStream_t stream)
{
    const float* ze  = (const float*)d_in[0];   // (16,64,64,64) fp32
    const float* emb = (const float*)d_in[1];   // (1024,64) fp32
    float* out = (float*)d_out;
    float* out_zq   = out;                 // 4194304
    float* out_loss = out + 4194304;       // 1
    float* out_idxf = out + 4194305;       // 65536

    char* w = (char*)d_ws;
    float*          ws_loss = (float*)(w + WS_LOSS);
    float*          enorm   = (float*)(w + WS_ENORM);
    unsigned short* ebf     = (unsigned short*)(w + WS_EBF);

    prep_kernel<<<4, 256, 0, stream>>>(emb, enorm, ebf, ws_loss);
    vq_kernel<<<512, 256, 0, stream>>>(ze, emb, enorm, ebf, out_zq, out_idxf, ws_loss);
    finalize_kernel<<<1, 1, 0, stream>>>(ws_loss, out_loss);
}

// Round 4
// 159.932 us; speedup vs baseline: 1.4234x; 1.0292x over previous
//
#include <hip/hip_runtime.h>

typedef short bf16x8 __attribute__((ext_vector_type(8)));
typedef float f32x4  __attribute__((ext_vector_type(4)));

#define N_POS 65536
#define KC    1024
#define CAP   512

// ws layout (bytes)
#define WS_LOSS  0
#define WS_ENORM 256
#define WS_EBF   4608   // 1024*64 bf16 (permuted) = 131072 B

__device__ __forceinline__ unsigned short f2bf(float f) {
    unsigned u = __float_as_uint(f);
    return (unsigned short)((u + 0x7fffu + ((u >> 16) & 1u)) >> 16);  // RTNE
}

// numpy pairwise sum (n=64): 8 accumulators, ((r0+r1)+(r2+r3))+((r4+r5)+(r6+r7)).
__device__ __forceinline__ float np_pairwise_sumsq64(const float* a) {
    float r[8];
    #pragma unroll
    for (int j = 0; j < 8; ++j) r[j] = __fmul_rn(a[j], a[j]);
    #pragma unroll
    for (int i = 8; i < 64; i += 8)
        #pragma unroll
        for (int j = 0; j < 8; ++j)
            r[j] = __fadd_rn(r[j], __fmul_rn(a[i + j], a[i + j]));
    return __fadd_rn(
        __fadd_rn(__fadd_rn(r[0], r[1]), __fadd_rn(r[2], r[3])),
        __fadd_rn(__fadd_rn(r[4], r[5]), __fadd_rn(r[6], r[7])));
}

// K1: enorm (numpy-exact) + bf16 codebook, MFMA-B-fragment-permuted:
// ebf[tile(64)][chunk j(8)][row r(16)][8 bf16], code = tile*16+r.
__global__ __launch_bounds__(256) void prep_kernel(
    const float* __restrict__ emb, float* __restrict__ enorm,
    unsigned short* __restrict__ ebf, float* __restrict__ loss)
{
    int k = blockIdx.x * 256 + threadIdx.x;
    if (k == 0) *loss = 0.0f;
    if (k < KC) {
        float e[64];
        #pragma unroll
        for (int l = 0; l < 64; ++l) e[l] = emb[k * 64 + l];
        enorm[k] = np_pairwise_sumsq64(e);
        int tile = k >> 4, r = k & 15;
        #pragma unroll
        for (int j = 0; j < 8; ++j) {
            bf16x8 v;
            #pragma unroll
            for (int m = 0; m < 8; ++m) v[m] = (short)f2bf(e[j * 8 + m]);
            *(bf16x8*)(ebf + tile * 1024 + j * 128 + r * 8) = v;
        }
    }
}

// K2: fused VQ. Block = 64 positions, 4 waves = 2 pos-groups x 2 K-halves
// (K-split doubles waves/CU at constant total MFMA + ebf traffic).
// bf16 MFMA filter (pass1 rowmin, pass2 collect), exact fp32 numpy rescore,
// lex-(score,k) select, fused z_q gather + loss.
__global__ __launch_bounds__(256, 4) void vq_kernel(
    const float* __restrict__ ze, const float* __restrict__ emb,
    const float* __restrict__ enormg, const unsigned short* __restrict__ ebf,
    float* __restrict__ out_zq, float* __restrict__ out_idxf,
    float* __restrict__ loss)
{
    __shared__ __align__(16) unsigned short zbf[64 * 64];  // 8192 B, XOR-swizzled
    __shared__ float zf[64 * 65];              // 16640 B (+1 pad: bank-spread)
    __shared__ float en_l[1024];               // 4096 B
    __shared__ float znorm_l[64], marg_l[64];  // 512 B
    __shared__ float rowmin2[64 * 2];          // 512 B  [pos][khalf]
    __shared__ int kch[64];                    // 256 B
    __shared__ unsigned cand[CAP];             // 2048 B  (pos<<16 | code)
    __shared__ float cscore[CAP];              // 2048 B
    __shared__ int lcnt;

    const int t = threadIdx.x;
    const int n0 = blockIdx.x * 64;
    const int gbase = (n0 >> 12) * 262144 + (n0 & 4095);
    if (t == 0) lcnt = 0;
    #pragma unroll
    for (int i = t; i < 1024; i += 256) en_l[i] = enormg[i];

    // stage: thread t -> pos p = t&63, dims [h*16, h*16+16), h = t>>6.
    // zf scalar writes conflict-free ((p+l)%32); zbf as 2 XOR-swizzled b128.
    {
        const int p = t & 63, h = t >> 6;
        float v[16];
        #pragma unroll
        for (int j = 0; j < 16; ++j) {
            v[j] = ze[gbase + p + (h * 16 + j) * 4096];
            zf[p * 65 + h * 16 + j] = v[j];
        }
        #pragma unroll
        for (int i = 0; i < 2; ++i) {
            int c = h * 2 + i;
            bf16x8 bv;
            #pragma unroll
            for (int m = 0; m < 8; ++m) bv[m] = (short)f2bf(v[i * 8 + m]);
            *(bf16x8*)&zbf[p * 64 + (c ^ (p & 7)) * 8] = bv;
        }
    }
    __syncthreads();

    // znorm (numpy pairwise) + margin = 1.67e-5*sum|z| + 5e-5
    if (t < 64) {
        float a[64];
        #pragma unroll
        for (int l = 0; l < 64; ++l) a[l] = zf[t * 65 + l];
        znorm_l[t] = np_pairwise_sumsq64(a);
        float S = 0.0f;
        #pragma unroll
        for (int l = 0; l < 64; ++l) S += fabsf(a[l]);
        marg_l[t] = 1.67e-5f * S + 5e-5f;
    }

    const int wv = t >> 6;
    const int lane = t & 63;
    const int r = lane & 15;   // code-in-tile / A row
    const int q = lane >> 4;   // quad -> K-chunk
    const int pg = wv >> 1;    // position group
    const int kh = wv & 1;     // K half
    const int wp = pg * 32;
    const int kbase = kh * 512;

    // A-fragments: A[m=lane&15][k=quad*8+j]; chunks q (K 0..31), q+4 (K 32..63)
    const int p0 = wp + r, p1 = wp + 16 + r;
    const int sw = r & 7;
    bf16x8 a00 = *(bf16x8*)&zbf[p0 * 64 + ((q)     ^ sw) * 8];
    bf16x8 a01 = *(bf16x8*)&zbf[p0 * 64 + ((q + 4) ^ sw) * 8];
    bf16x8 a10 = *(bf16x8*)&zbf[p1 * 64 + ((q)     ^ sw) * 8];
    bf16x8 a11 = *(bf16x8*)&zbf[p1 * 64 + ((q + 4) ^ sw) * 8];
    const unsigned short* bptr = ebf + (kh * 32) * 1024 + q * 128 + r * 8;

    // ---- pass 1: per-row min over this wave's 512 codes ----
    float rm[8];
    #pragma unroll
    for (int i = 0; i < 8; ++i) rm[i] = 1e30f;
    #pragma unroll 4
    for (int tile = 0; tile < 32; ++tile) {
        bf16x8 b0 = *(const bf16x8*)(bptr + tile * 1024);
        bf16x8 b1 = *(const bf16x8*)(bptr + tile * 1024 + 512);
        f32x4 c0 = {0.f, 0.f, 0.f, 0.f}, c1 = {0.f, 0.f, 0.f, 0.f};
        c0 = __builtin_amdgcn_mfma_f32_16x16x32_bf16(a00, b0, c0, 0, 0, 0);
        c0 = __builtin_amdgcn_mfma_f32_16x16x32_bf16(a01, b1, c0, 0, 0, 0);
        c1 = __builtin_amdgcn_mfma_f32_16x16x32_bf16(a10, b0, c1, 0, 0, 0);
        c1 = __builtin_amdgcn_mfma_f32_16x16x32_bf16(a11, b1, c1, 0, 0, 0);
        float en = en_l[kbase + tile * 16 + r];
        #pragma unroll
        for (int i = 0; i < 4; ++i) {
            rm[i]     = fminf(rm[i],     fmaf(c0[i], -2.0f, en));
            rm[4 + i] = fminf(rm[4 + i], fmaf(c1[i], -2.0f, en));
        }
    }
    #pragma unroll
    for (int i = 0; i < 8; ++i) {
        float v = rm[i];
        v = fminf(v, __shfl_xor(v, 1, 16));
        v = fminf(v, __shfl_xor(v, 2, 16));
        v = fminf(v, __shfl_xor(v, 4, 16));
        v = fminf(v, __shfl_xor(v, 8, 16));
        rm[i] = v;
        int row = wp + ((i >= 4) ? 16 : 0) + q * 4 + (i & 3);
        if (r == 0) rowmin2[row * 2 + kh] = v;
    }
    __syncthreads();   // rowmin2 + marg_l visible

    float thr[8];
    #pragma unroll
    for (int i = 0; i < 8; ++i) {
        int row = wp + ((i >= 4) ? 16 : 0) + q * 4 + (i & 3);
        thr[i] = fminf(rowmin2[row * 2], rowmin2[row * 2 + 1]) + marg_l[row];
    }

    // ---- pass 2: collect candidates (score <= global rowmin + margin) ----
    #pragma unroll 4
    for (int tile = 0; tile < 32; ++tile) {
        bf16x8 b0 = *(const bf16x8*)(bptr + tile * 1024);
        bf16x8 b1 = *(const bf16x8*)(bptr + tile * 1024 + 512);
        f32x4 c0 = {0.f, 0.f, 0.f, 0.f}, c1 = {0.f, 0.f, 0.f, 0.f};
        c0 = __builtin_amdgcn_mfma_f32_16x16x32_bf16(a00, b0, c0, 0, 0, 0);
        c0 = __builtin_amdgcn_mfma_f32_16x16x32_bf16(a01, b1, c0, 0, 0, 0);
        c1 = __builtin_amdgcn_mfma_f32_16x16x32_bf16(a10, b0, c1, 0, 0, 0);
        c1 = __builtin_amdgcn_mfma_f32_16x16x32_bf16(a11, b1, c1, 0, 0, 0);
        float en = en_l[kbase + tile * 16 + r];
        int code = kbase + tile * 16 + r;
        #pragma unroll
        for (int i = 0; i < 4; ++i) {
            if (fmaf(c0[i], -2.0f, en) <= thr[i]) {
                int ci = atomicAdd(&lcnt, 1);
                if (ci < CAP) cand[ci] = ((unsigned)(wp + q * 4 + i) << 16) | code;
            }
            if (fmaf(c1[i], -2.0f, en) <= thr[4 + i]) {
                int ci = atomicAdd(&lcnt, 1);
                if (ci < CAP) cand[ci] = ((unsigned)(wp + 16 + q * 4 + i) << 16) | code;
            }
        }
    }
    __syncthreads();

    // ---- exact fp32 numpy rescore (R2-verified recipe, bit-identical) ----
    int cnt = lcnt; if (cnt > CAP) cnt = CAP;
    for (int i = t; i < cnt; i += 256) {
        unsigned e = cand[i];
        int p = e >> 16, k = e & 0xffff;
        const float* ep = emb + k * 64;
        const float* zp = &zf[p * 65];
        float acc = 0.0f;
        #pragma unroll
        for (int l = 0; l < 64; ++l) acc = fmaf(zp[l], ep[l], acc);  // sgemm order
        float v = __fadd_rn(znorm_l[p], en_l[k]);
        cscore[i] = __fsub_rn(v, __fmul_rn(2.0f, acc));
    }
    __syncthreads();

    // ---- select: lexicographic (score, k) == numpy first occurrence ----
    if (t < 64) {
        float best = 1e30f; int bk = 1 << 20;
        for (int i = 0; i < cnt; ++i) {
            unsigned e = cand[i];
            if ((int)(e >> 16) == t) {
                int k = e & 0xffff; float sc = cscore[i];
                if (sc < best || (sc == best && k < bk)) { best = sc; bk = k; }
            }
        }
        kch[t] = bk;
        out_idxf[n0 + t] = (float)bk;
    }
    __syncthreads();

    // ---- fused epilogue: z_q gather + loss partial ----
    {
        const int p = t & 63, l0 = (t >> 6) * 16;
        const int k = kch[p];
        const float* ep = emb + k * 64;
        float ls = 0.0f;
        #pragma unroll
        for (int j = 0; j < 16; ++j) {
            int l = l0 + j;
            float qv = ep[l];
            float zv = zf[p * 65 + l];
            out_zq[gbase + p + l * 4096] = qv;
            float d = qv - zv;
            ls = fmaf(d, d, ls);
        }
        #pragma unroll
        for (int off = 32; off > 0; off >>= 1) ls += __shfl_down(ls, off, 64);
        if (lane == 0) atomicAdd(loss, ls);
    }
}

// K3: loss = 1.25 * mean(diff^2)
__global__ void finalize_kernel(const float* __restrict__ loss, float* __restrict__ out_loss)
{
    *out_loss = 1.25f * (*loss) / 4194304.0f;
}

extern "C" void kernel_launch(void* const* d_in, const int* in_sizes, int n_in,
                              void* d_out, int out_size, void* d_ws, size_t ws_size,
                              hipStream_t stream)
{
    const float* ze  = (const float*)d_in[0];   // (16,64,64,64) fp32
    const float* emb = (const float*)d_in[1];   // (1024,64) fp32
    float* out = (float*)d_out;
    float* out_zq   = out;                 // 4194304
    float* out_loss = out + 4194304;       // 1
    float* out_idxf = out + 4194305;       // 65536

    char* w = (char*)d_ws;
    float*          ws_loss = (float*)(w + WS_LOSS);
    float*          enorm   = (float*)(w + WS_ENORM);
    unsigned short* ebf     = (unsigned short*)(w + WS_EBF);

    prep_kernel<<<4, 256, 0, stream>>>(emb, enorm, ebf, ws_loss);
    vq_kernel<<<1024, 256, 0, stream>>>(ze, emb, enorm, ebf, out_zq, out_idxf, ws_loss);
    finalize_kernel<<<1, 1, 0, stream>>>(ws_loss, out_loss);
}

// Round 5
// 157.010 us; speedup vs baseline: 1.4499x; 1.0186x over previous
//
#include <hip/hip_runtime.h>

typedef short bf16x8 __attribute__((ext_vector_type(8)));
typedef float f32x4  __attribute__((ext_vector_type(4)));

#define CAP 12

// ws layout (bytes)
#define WS_LOSS 0
#define WS_EBF  64      // 1024*64 bf16 (permuted) = 131072 B

// dynamic LDS carve (bytes)
#define L_EBF   0        // 131072  (65536 shorts)
#define L_ZBF   131072   // 16384   (128 pos x 64 dims bf16, XOR-swizzled)
#define L_MARG  147456   // 512
#define L_CCNT  147968   // 512
#define L_CSLOT 148480   // 128*CAP*4 = 6144
#define L_TOTAL 154624

__device__ __forceinline__ unsigned short f2bf(float f) {
    unsigned u = __float_as_uint(f);
    return (unsigned short)((u + 0x7fffu + ((u >> 16) & 1u)) >> 16);  // RTNE
}

// numpy pairwise sum (n=64): 8 accumulators, ((r0+r1)+(r2+r3))+((r4+r5)+(r6+r7)).
__device__ __forceinline__ float np_pairwise_sumsq64(const float* a) {
    float r[8];
    #pragma unroll
    for (int j = 0; j < 8; ++j) r[j] = __fmul_rn(a[j], a[j]);
    #pragma unroll
    for (int i = 8; i < 64; i += 8)
        #pragma unroll
        for (int j = 0; j < 8; ++j)
            r[j] = __fadd_rn(r[j], __fmul_rn(a[i + j], a[i + j]));
    return __fadd_rn(
        __fadd_rn(__fadd_rn(r[0], r[1]), __fadd_rn(r[2], r[3])),
        __fadd_rn(__fadd_rn(r[4], r[5]), __fadd_rn(r[6], r[7])));
}

// K1: bf16 codebook in MFMA-B-fragment-permuted layout + zero loss.
// ebf[tile(64)][chunk j(8)][row r(16)][8 bf16], code = tile*16+r.
__global__ __launch_bounds__(256) void prep_kernel(
    const float* __restrict__ emb, unsigned short* __restrict__ ebf,
    float* __restrict__ loss)
{
    int k = blockIdx.x * 256 + threadIdx.x;
    if (k == 0) *loss = 0.0f;
    if (k < 1024) {
        float e[64];
        #pragma unroll
        for (int l = 0; l < 64; ++l) e[l] = emb[k * 64 + l];
        int tile = k >> 4, r = k & 15;
        #pragma unroll
        for (int j = 0; j < 8; ++j) {
            bf16x8 v;
            #pragma unroll
            for (int m = 0; m < 8; ++m) v[m] = (short)f2bf(e[j * 8 + m]);
            *(bf16x8*)(ebf + tile * 1024 + j * 128 + r * 8) = v;
        }
    }
}

// K2: fused VQ, full codebook in LDS (1 block/CU).
// Block = 128 positions; wave w = 32 positions x all 1024 codes (no K-split).
// Waves 0-1: stage z (fp32 in regs) + zbf + margin; waves 2-3: ebf -> LDS.
// Filter = -2*dot only (enorm folded into margin). Exact fp32 numpy rescore
// per-position by owner thread; fused z_q gather + loss.
__global__ __launch_bounds__(256, 1) void vq_kernel(
    const float* __restrict__ ze, const float* __restrict__ emb,
    const unsigned short* __restrict__ ebf,
    float* __restrict__ out_zq, float* __restrict__ out_idxf,
    float* __restrict__ loss)
{
    extern __shared__ char smem[];
    unsigned short* ebf_l = (unsigned short*)(smem + L_EBF);
    unsigned short* zbf   = (unsigned short*)(smem + L_ZBF);
    float*          marg_l = (float*)(smem + L_MARG);
    int*            ccnt   = (int*)(smem + L_CCNT);
    int*            cslot  = (int*)(smem + L_CSLOT);

    const int t = threadIdx.x;
    const int n0 = blockIdx.x * 128;
    const int gbase = (n0 >> 12) * 262144 + (n0 & 4095);

    float z[64];
    float znorm = 0.0f;

    if (t < 128) {
        // ---- stage z: pos p = t, 64 strided coalesced loads ----
        const float* zp = ze + gbase + t;
        #pragma unroll
        for (int l = 0; l < 64; ++l) z[l] = zp[l * 4096];
        ccnt[t] = 0;
        znorm = np_pairwise_sumsq64(z);
        float S = 0.0f;
        #pragma unroll
        for (int l = 0; l < 64; ++l) S += fabsf(z[l]);
        // bf16-filter bound + dropped-enorm slack (en_k <= 6.1e-5) + safety
        marg_l[t] = 1.67e-5f * S + 2.0e-4f;
        // zbf: 8 XOR-swizzled b128 writes
        const int sw = t & 7;
        #pragma unroll
        for (int c = 0; c < 8; ++c) {
            bf16x8 bv;
            #pragma unroll
            for (int m = 0; m < 8; ++m) bv[m] = (short)f2bf(z[c * 8 + m]);
            *(bf16x8*)&zbf[t * 64 + ((c ^ sw) * 8)] = bv;
        }
    } else {
        // ---- stage full codebook into LDS: 131072 B over 128 threads ----
        const int tt = t - 128;
        #pragma unroll 8
        for (int it = 0; it < 64; ++it) {
            int off = it * 1024 + tt * 8;   // shorts; 16B per thread per iter
            *(bf16x8*)&ebf_l[off] = *(const bf16x8*)&ebf[off];
        }
    }
    __syncthreads();

    const int wv = t >> 6;
    const int lane = t & 63;
    const int r = lane & 15;     // code-in-tile / A-row selector
    const int q = lane >> 4;     // quad -> K-chunk
    const int wp = wv * 32;      // wave's first position
    const int p0 = wp + r, p1 = wp + 16 + r;
    const int sw = r & 7;        // (p0&7)==(p1&7)==r&7

    // A-fragments: A[m=lane&15][k=quad*8+j] (R4-proven layout)
    bf16x8 a00 = *(bf16x8*)&zbf[p0 * 64 + ((q       ^ sw) * 8)];
    bf16x8 a01 = *(bf16x8*)&zbf[p0 * 64 + (((q + 4) ^ sw) * 8)];
    bf16x8 a10 = *(bf16x8*)&zbf[p1 * 64 + ((q       ^ sw) * 8)];
    bf16x8 a11 = *(bf16x8*)&zbf[p1 * 64 + (((q + 4) ^ sw) * 8)];
    const unsigned short* bptr = ebf_l + q * 128 + r * 8;

    // ---- pass 1: per-row min of filter g = -2*dot over all 1024 codes ----
    float rm[8];
    #pragma unroll
    for (int i = 0; i < 8; ++i) rm[i] = 1e30f;
    #pragma unroll 4
    for (int tile = 0; tile < 64; ++tile) {
        bf16x8 b0 = *(const bf16x8*)(bptr + tile * 1024);
        bf16x8 b1 = *(const bf16x8*)(bptr + tile * 1024 + 512);
        f32x4 c0 = {0.f, 0.f, 0.f, 0.f}, c1 = {0.f, 0.f, 0.f, 0.f};
        c0 = __builtin_amdgcn_mfma_f32_16x16x32_bf16(a00, b0, c0, 0, 0, 0);
        c0 = __builtin_amdgcn_mfma_f32_16x16x32_bf16(a01, b1, c0, 0, 0, 0);
        c1 = __builtin_amdgcn_mfma_f32_16x16x32_bf16(a10, b0, c1, 0, 0, 0);
        c1 = __builtin_amdgcn_mfma_f32_16x16x32_bf16(a11, b1, c1, 0, 0, 0);
        #pragma unroll
        for (int i = 0; i < 4; ++i) {
            rm[i]     = fminf(rm[i],     c0[i] * -2.0f);
            rm[4 + i] = fminf(rm[4 + i], c1[i] * -2.0f);
        }
    }
    float thr[8];
    #pragma unroll
    for (int i = 0; i < 8; ++i) {
        float v = rm[i];
        v = fminf(v, __shfl_xor(v, 1, 16));
        v = fminf(v, __shfl_xor(v, 2, 16));
        v = fminf(v, __shfl_xor(v, 4, 16));
        v = fminf(v, __shfl_xor(v, 8, 16));
        int row = wp + ((i >= 4) ? 16 : 0) + q * 4 + (i & 3);
        thr[i] = v + marg_l[row];
    }

    // ---- pass 2: collect candidates ----
    #pragma unroll 4
    for (int tile = 0; tile < 64; ++tile) {
        bf16x8 b0 = *(const bf16x8*)(bptr + tile * 1024);
        bf16x8 b1 = *(const bf16x8*)(bptr + tile * 1024 + 512);
        f32x4 c0 = {0.f, 0.f, 0.f, 0.f}, c1 = {0.f, 0.f, 0.f, 0.f};
        c0 = __builtin_amdgcn_mfma_f32_16x16x32_bf16(a00, b0, c0, 0, 0, 0);
        c0 = __builtin_amdgcn_mfma_f32_16x16x32_bf16(a01, b1, c0, 0, 0, 0);
        c1 = __builtin_amdgcn_mfma_f32_16x16x32_bf16(a10, b0, c1, 0, 0, 0);
        c1 = __builtin_amdgcn_mfma_f32_16x16x32_bf16(a11, b1, c1, 0, 0, 0);
        int code = tile * 16 + r;
        #pragma unroll
        for (int i = 0; i < 4; ++i) {
            if (c0[i] * -2.0f <= thr[i]) {
                int pp = wp + q * 4 + i;
                int ci = atomicAdd(&ccnt[pp], 1);
                if (ci < CAP) cslot[pp * CAP + ci] = code;
            }
            if (c1[i] * -2.0f <= thr[4 + i]) {
                int pp = wp + 16 + q * 4 + i;
                int ci = atomicAdd(&ccnt[pp], 1);
                if (ci < CAP) cslot[pp * CAP + ci] = code;
            }
        }
    }
    __syncthreads();

    // ---- exact fp32 numpy rescore + select + fused epilogue (owner thread) ----
    if (t < 128) {
        int cnt = ccnt[t]; if (cnt > CAP) cnt = CAP;
        float best = 1e30f; int bk = 1 << 20;
        for (int c = 0; c < cnt; ++c) {
            int k = cslot[t * CAP + c];
            float e[64];
            const float4* er = (const float4*)(emb + k * 64);
            #pragma unroll
            for (int j = 0; j < 16; ++j) {
                float4 v = er[j];
                e[4*j] = v.x; e[4*j+1] = v.y; e[4*j+2] = v.z; e[4*j+3] = v.w;
            }
            float en = np_pairwise_sumsq64(e);       // == prep's enorm, bit-exact
            float acc = 0.0f;
            #pragma unroll
            for (int l = 0; l < 64; ++l) acc = fmaf(z[l], e[l], acc);  // sgemm order
            float sc = __fsub_rn(__fadd_rn(znorm, en), __fmul_rn(2.0f, acc));
            if (sc < best || (sc == best && k < bk)) { best = sc; bk = k; }
        }
        out_idxf[n0 + t] = (float)bk;

        const float4* er = (const float4*)(emb + bk * 64);
        float ls = 0.0f;
        #pragma unroll
        for (int j = 0; j < 16; ++j) {
            float4 v = er[j];
            float vv[4] = {v.x, v.y, v.z, v.w};
            #pragma unroll
            for (int m = 0; m < 4; ++m) {
                int l = 4 * j + m;
                out_zq[gbase + t + l * 4096] = vv[m];
                float d = vv[m] - z[l];
                ls = fmaf(d, d, ls);
            }
        }
        #pragma unroll
        for (int off = 32; off > 0; off >>= 1) ls += __shfl_down(ls, off, 64);
        if ((t & 63) == 0) atomicAdd(loss, ls);
    }
}

// K3: loss = 1.25 * mean(diff^2)
__global__ void finalize_kernel(const float* __restrict__ loss, float* __restrict__ out_loss)
{
    *out_loss = 1.25f * (*loss) / 4194304.0f;
}

extern "C" void kernel_launch(void* const* d_in, const int* in_sizes, int n_in,
                              void* d_out, int out_size, void* d_ws, size_t ws_size,
                              hipStream_t stream)
{
    const float* ze  = (const float*)d_in[0];   // (16,64,64,64) fp32
    const float* emb = (const float*)d_in[1];   // (1024,64) fp32
    float* out = (float*)d_out;
    float* out_zq   = out;                 // 4194304
    float* out_loss = out + 4194304;       // 1
    float* out_idxf = out + 4194305;       // 65536

    char* w = (char*)d_ws;
    float*          ws_loss = (float*)(w + WS_LOSS);
    unsigned short* ebf     = (unsigned short*)(w + WS_EBF);

    // allow >64KB dynamic LDS (no-op if already permitted)
    static bool attr_set = false;
    if (!attr_set) {
        hipFuncSetAttribute((const void*)vq_kernel,
                            hipFuncAttributeMaxDynamicSharedMemorySize, L_TOTAL);
        attr_set = true;
    }

    prep_kernel<<<4, 256, 0, stream>>>(emb, ebf, ws_loss);
    vq_kernel<<<512, 256, L_TOTAL, stream>>>(ze, emb, ebf, out_zq, out_idxf, ws_loss);
    finalize_kernel<<<1, 1, 0, stream>>>(ws_loss, out_loss);
}

// Round 6
// 141.489 us; speedup vs baseline: 1.6089x; 1.1097x over previous
//
#include <hip/hip_runtime.h>

typedef short bf16x8 __attribute__((ext_vector_type(8)));
typedef float f32x4  __attribute__((ext_vector_type(4)));

#define CAP 12

// ws layout (bytes)
#define WS_LOSS 0
#define WS_DONE 8
#define WS_EBF  64      // 1024*64 bf16 (permuted) = 131072 B

// dynamic LDS carve (bytes)
#define L_EBF   0        // 131072 (zbf temp lives in first 32 KB before staging)
#define L_MARG  131072   // 1024
#define L_CCNT  132096   // 1024
#define L_CSLOT 133120   // 256*CAP*4 = 12288
#define L_TOTAL 145408

__device__ __forceinline__ unsigned short f2bf(float f) {
    unsigned u = __float_as_uint(f);
    return (unsigned short)((u + 0x7fffu + ((u >> 16) & 1u)) >> 16);  // RTNE
}

// numpy pairwise sum (n=64): 8 accumulators, ((r0+r1)+(r2+r3))+((r4+r5)+(r6+r7)).
__device__ __forceinline__ float np_pairwise_sumsq64(const float* a) {
    float r[8];
    #pragma unroll
    for (int j = 0; j < 8; ++j) r[j] = __fmul_rn(a[j], a[j]);
    #pragma unroll
    for (int i = 8; i < 64; i += 8)
        #pragma unroll
        for (int j = 0; j < 8; ++j)
            r[j] = __fadd_rn(r[j], __fmul_rn(a[i + j], a[i + j]));
    return __fadd_rn(
        __fadd_rn(__fadd_rn(r[0], r[1]), __fadd_rn(r[2], r[3])),
        __fadd_rn(__fadd_rn(r[4], r[5]), __fadd_rn(r[6], r[7])));
}

// K1: bf16 codebook in MFMA-B-fragment-permuted layout + zero loss/done.
// ebf[tile(64)][chunk j(8)][row r(16)][8 bf16], code = tile*16+r.
__global__ __launch_bounds__(256) void prep_kernel(
    const float* __restrict__ emb, unsigned short* __restrict__ ebf,
    float* __restrict__ loss, int* __restrict__ done)
{
    int k = blockIdx.x * 256 + threadIdx.x;
    if (k == 0) { *loss = 0.0f; *done = 0; }
    if (k < 1024) {
        float e[64];
        #pragma unroll
        for (int l = 0; l < 64; ++l) e[l] = emb[k * 64 + l];
        int tile = k >> 4, r = k & 15;
        #pragma unroll
        for (int j = 0; j < 8; ++j) {
            bf16x8 v;
            #pragma unroll
            for (int m = 0; m < 8; ++m) v[m] = (short)f2bf(e[j * 8 + m]);
            *(bf16x8*)(ebf + tile * 1024 + j * 128 + r * 8) = v;
        }
    }
}

// K2: fused VQ. 256 pos/block, grid 256 (1 generation, 1 block/CU).
// Wave = 64 positions x all 1024 codes; 8 MFMA per b-frag pair; depth-2
// register prefetch of b-frags; full codebook in LDS; exact fp32 numpy
// rescore; fused z_q/loss epilogue; last block finalizes loss.
__global__ __launch_bounds__(256)
__attribute__((amdgpu_waves_per_eu(1, 1)))
void vq_kernel(
    const float* __restrict__ ze, const float* __restrict__ emb,
    const unsigned short* __restrict__ ebf,
    float* __restrict__ out_zq, float* __restrict__ out_idxf,
    float* __restrict__ loss, int* __restrict__ done,
    float* __restrict__ out_loss)
{
    extern __shared__ char smem[];
    unsigned short* ebf_l  = (unsigned short*)(smem + L_EBF);
    unsigned short* zbf    = (unsigned short*)(smem + L_EBF);   // temp, pre-staging
    float*          marg_l = (float*)(smem + L_MARG);
    int*            ccnt   = (int*)(smem + L_CCNT);
    int*            cslot  = (int*)(smem + L_CSLOT);

    const int t = threadIdx.x;
    const int n0 = blockIdx.x * 256;
    const int gbase = (n0 >> 12) * 262144 + (n0 & 4095);

    // ---- phase A: stage z (regs), znorm/margin, zbf (XOR-swizzled) ----
    float z[64];
    {
        const float* zp = ze + gbase + t;
        #pragma unroll
        for (int l = 0; l < 64; ++l) z[l] = zp[l * 4096];
    }
    ccnt[t] = 0;
    const float znorm = np_pairwise_sumsq64(z);
    {
        float S = 0.0f;
        #pragma unroll
        for (int l = 0; l < 64; ++l) S += fabsf(z[l]);
        marg_l[t] = 1.67e-5f * S + 2.0e-4f;   // R5-proven filter margin
    }
    {
        const int swt = t & 7;
        #pragma unroll
        for (int c = 0; c < 8; ++c) {
            bf16x8 bv;
            #pragma unroll
            for (int m = 0; m < 8; ++m) bv[m] = (short)f2bf(z[c * 8 + m]);
            *(bf16x8*)&zbf[t * 64 + ((c ^ swt) * 8)] = bv;
        }
    }
    __syncthreads();

    // ---- A-fragments: 4 row-groups x 2 K-chunks (A[m=lane&15][k=q*8+j]) ----
    const int wv = t >> 6, lane = t & 63;
    const int r = lane & 15, q = lane >> 4;
    const int wp = wv * 64;
    const int sw = r & 7;
    bf16x8 a0[4], a1[4];
    #pragma unroll
    for (int rg = 0; rg < 4; ++rg) {
        int pg = wp + rg * 16 + r;
        a0[rg] = *(bf16x8*)&zbf[pg * 64 + ((q ^ sw) * 8)];
        a1[rg] = *(bf16x8*)&zbf[pg * 64 + (((q + 4) ^ sw) * 8)];
    }
    __syncthreads();   // all zbf reads done before overwrite

    // ---- phase B: stage full codebook into LDS (131072 B, b128 copies) ----
    {
        const bf16x8* src = (const bf16x8*)ebf;
        bf16x8* dst = (bf16x8*)ebf_l;
        #pragma unroll 8
        for (int i = 0; i < 32; ++i) dst[t + i * 256] = src[t + i * 256];
    }
    __syncthreads();

    const unsigned short* bptr = ebf_l + q * 128 + r * 8;

    // ---- pass 1: per-row max of c = z.e over all 1024 codes ----
    float rm[16];
    #pragma unroll
    for (int i = 0; i < 16; ++i) rm[i] = -1e30f;
    {
        bf16x8 pb0[2], pb1[2];
        pb0[0] = *(const bf16x8*)(bptr);
        pb1[0] = *(const bf16x8*)(bptr + 512);
        pb0[1] = *(const bf16x8*)(bptr + 1024);
        pb1[1] = *(const bf16x8*)(bptr + 1536);
        #pragma unroll 4
        for (int tile = 0; tile < 64; ++tile) {
            bf16x8 b0 = pb0[tile & 1], b1 = pb1[tile & 1];
            int nt = tile + 2; if (nt > 63) nt = 63;
            pb0[tile & 1] = *(const bf16x8*)(bptr + nt * 1024);
            pb1[tile & 1] = *(const bf16x8*)(bptr + nt * 1024 + 512);
            #pragma unroll
            for (int rg = 0; rg < 4; ++rg) {
                f32x4 c = {0.f, 0.f, 0.f, 0.f};
                c = __builtin_amdgcn_mfma_f32_16x16x32_bf16(a0[rg], b0, c, 0, 0, 0);
                c = __builtin_amdgcn_mfma_f32_16x16x32_bf16(a1[rg], b1, c, 0, 0, 0);
                #pragma unroll
                for (int i = 0; i < 4; ++i)
                    rm[rg * 4 + i] = fmaxf(rm[rg * 4 + i], c[i]);
            }
        }
    }
    // cross-lane max over the 16 codes (lanes sharing q), then threshold:
    // score = -2c + const  =>  candidate iff c >= maxc - marg/2
    float thr[16];
    #pragma unroll
    for (int j = 0; j < 16; ++j) {
        float v = rm[j];
        v = fmaxf(v, __shfl_xor(v, 1, 16));
        v = fmaxf(v, __shfl_xor(v, 2, 16));
        v = fmaxf(v, __shfl_xor(v, 4, 16));
        v = fmaxf(v, __shfl_xor(v, 8, 16));
        int row = wp + (j >> 2) * 16 + q * 4 + (j & 3);
        thr[j] = v - 0.5f * marg_l[row];
    }

    // ---- pass 2: collect candidates ----
    {
        bf16x8 pb0[2], pb1[2];
        pb0[0] = *(const bf16x8*)(bptr);
        pb1[0] = *(const bf16x8*)(bptr + 512);
        pb0[1] = *(const bf16x8*)(bptr + 1024);
        pb1[1] = *(const bf16x8*)(bptr + 1536);
        #pragma unroll 4
        for (int tile = 0; tile < 64; ++tile) {
            bf16x8 b0 = pb0[tile & 1], b1 = pb1[tile & 1];
            int nt = tile + 2; if (nt > 63) nt = 63;
            pb0[tile & 1] = *(const bf16x8*)(bptr + nt * 1024);
            pb1[tile & 1] = *(const bf16x8*)(bptr + nt * 1024 + 512);
            int code = tile * 16 + r;
            #pragma unroll
            for (int rg = 0; rg < 4; ++rg) {
                f32x4 c = {0.f, 0.f, 0.f, 0.f};
                c = __builtin_amdgcn_mfma_f32_16x16x32_bf16(a0[rg], b0, c, 0, 0, 0);
                c = __builtin_amdgcn_mfma_f32_16x16x32_bf16(a1[rg], b1, c, 0, 0, 0);
                #pragma unroll
                for (int i = 0; i < 4; ++i) {
                    if (c[i] >= thr[rg * 4 + i]) {
                        int pp = wp + rg * 16 + q * 4 + i;
                        int ci = atomicAdd(&ccnt[pp], 1);
                        if (ci < CAP) cslot[pp * CAP + ci] = code;
                    }
                }
            }
        }
    }
    __syncthreads();

    // ---- exact fp32 numpy rescore + lex-(score,k) select (thread t = pos t) ----
    int cnt = ccnt[t]; if (cnt > CAP) cnt = CAP;
    float best = 1e30f; int bk = 1 << 20;
    for (int c = 0; c < cnt; ++c) {
        int k = cslot[t * CAP + c];
        float e[64];
        const float4* er = (const float4*)(emb + k * 64);
        #pragma unroll
        for (int j = 0; j < 16; ++j) {
            float4 v = er[j];
            e[4*j] = v.x; e[4*j+1] = v.y; e[4*j+2] = v.z; e[4*j+3] = v.w;
        }
        float en = np_pairwise_sumsq64(e);          // bit-exact numpy enorm
        float acc = 0.0f;
        #pragma unroll
        for (int l = 0; l < 64; ++l) acc = fmaf(z[l], e[l], acc);  // sgemm order
        float sc = __fsub_rn(__fadd_rn(znorm, en), __fmul_rn(2.0f, acc));
        if (sc < best || (sc == best && k < bk)) { best = sc; bk = k; }
    }
    out_idxf[n0 + t] = (float)bk;

    // ---- fused epilogue: z_q gather + loss partial ----
    {
        const float4* er = (const float4*)(emb + bk * 64);
        float ls = 0.0f;
        #pragma unroll
        for (int j = 0; j < 16; ++j) {
            float4 v = er[j];
            float vv[4] = {v.x, v.y, v.z, v.w};
            #pragma unroll
            for (int m = 0; m < 4; ++m) {
                int l = 4 * j + m;
                out_zq[gbase + t + l * 4096] = vv[m];
                float d = vv[m] - z[l];
                ls = fmaf(d, d, ls);
            }
        }
        #pragma unroll
        for (int off = 32; off > 0; off >>= 1) ls += __shfl_down(ls, off, 64);
        if (lane == 0) atomicAdd(loss, ls);
    }

    // ---- last block finalizes loss (device-scope atomics; no spinning) ----
    __syncthreads();
    if (t == 0) {
        __threadfence();
        int old = atomicAdd(done, 1);
        if (old == (int)gridDim.x - 1) {
            __threadfence();
            float total = atomicAdd(loss, 0.0f);   // coherent read
            *out_loss = 1.25f * total / 4194304.0f;
        }
    }
}

extern "C" void kernel_launch(void* const* d_in, const int* in_sizes, int n_in,
                              void* d_out, int out_size, void* d_ws, size_t ws_size,
                              hipStream_t stream)
{
    const float* ze  = (const float*)d_in[0];   // (16,64,64,64) fp32
    const float* emb = (const float*)d_in[1];   // (1024,64) fp32
    float* out = (float*)d_out;
    float* out_zq   = out;                 // 4194304
    float* out_loss = out + 4194304;       // 1
    float* out_idxf = out + 4194305;       // 65536

    char* w = (char*)d_ws;
    float*          ws_loss = (float*)(w + WS_LOSS);
    int*            ws_done = (int*)(w + WS_DONE);
    unsigned short* ebf     = (unsigned short*)(w + WS_EBF);

    // allow >64KB dynamic LDS (no-op if already permitted)
    static bool attr_set = false;
    if (!attr_set) {
        hipFuncSetAttribute((const void*)vq_kernel,
                            hipFuncAttributeMaxDynamicSharedMemorySize, L_TOTAL);
        attr_set = true;
    }

    prep_kernel<<<4, 256, 0, stream>>>(emb, ebf, ws_loss, ws_done);
    vq_kernel<<<256, 256, L_TOTAL, stream>>>(ze, emb, ebf, out_zq, out_idxf,
                                             ws_loss, ws_done, out_loss);
}

// Round 7
// 139.503 us; speedup vs baseline: 1.6319x; 1.0142x over previous
//
#include <hip/hip_runtime.h>

typedef short bf16x8 __attribute__((ext_vector_type(8)));
typedef float f32x4  __attribute__((ext_vector_type(4)));

#define CAP 12

// ws layout (bytes)
#define WS_LOSS 0
#define WS_DONE 8
#define WS_EBF  64      // 1024*64 bf16 (permuted) = 131072 B

// dynamic LDS carve (bytes)
#define L_EBF    0       // 131072
#define L_MARG   131072  // 1024
#define L_CCNT   132096  // 1024
#define L_KCH    133120  // 1024
#define L_ROWMAX 134144  // 2048  (256 pos x 2 K-halves)
#define L_CSLOT  136192  // 256*CAP*4 = 12288
#define L_TOTAL  148480

__device__ __forceinline__ unsigned short f2bf(float f) {
    unsigned u = __float_as_uint(f);
    return (unsigned short)((u + 0x7fffu + ((u >> 16) & 1u)) >> 16);  // RTNE
}

// numpy pairwise sum (n=64): 8 accumulators, ((r0+r1)+(r2+r3))+((r4+r5)+(r6+r7)).
__device__ __forceinline__ float np_pairwise_sumsq64(const float* a) {
    float r[8];
    #pragma unroll
    for (int j = 0; j < 8; ++j) r[j] = __fmul_rn(a[j], a[j]);
    #pragma unroll
    for (int i = 8; i < 64; i += 8)
        #pragma unroll
        for (int j = 0; j < 8; ++j)
            r[j] = __fadd_rn(r[j], __fmul_rn(a[i + j], a[i + j]));
    return __fadd_rn(
        __fadd_rn(__fadd_rn(r[0], r[1]), __fadd_rn(r[2], r[3])),
        __fadd_rn(__fadd_rn(r[4], r[5]), __fadd_rn(r[6], r[7])));
}

// K1: bf16 codebook in MFMA-B-fragment-permuted layout + zero loss/done.
// ebf[tile(64)][chunk j(8)][row r(16)][8 bf16], code = tile*16+r.
__global__ __launch_bounds__(256) void prep_kernel(
    const float* __restrict__ emb, unsigned short* __restrict__ ebf,
    float* __restrict__ loss, int* __restrict__ done)
{
    int k = blockIdx.x * 256 + threadIdx.x;
    if (k == 0) { *loss = 0.0f; *done = 0; }
    if (k < 1024) {
        float e[64];
        #pragma unroll
        for (int l = 0; l < 64; ++l) e[l] = emb[k * 64 + l];
        int tile = k >> 4, r = k & 15;
        #pragma unroll
        for (int j = 0; j < 8; ++j) {
            bf16x8 v;
            #pragma unroll
            for (int m = 0; m < 8; ++m) v[m] = (short)f2bf(e[j * 8 + m]);
            *(bf16x8*)(ebf + tile * 1024 + j * 128 + r * 8) = v;
        }
    }
}

// K2: fused VQ. 512 thr (8 waves = 2 waves/SIMD), 256 pos/block, grid 256.
// Waves split K: wave = 64 positions x 512 codes (K-half); rowmax merged in
// LDS. Full codebook in LDS; a-frags built from global ze; exact fp32 numpy
// rescore; split-dim epilogue; last block finalizes loss.
__global__ __launch_bounds__(512)
__attribute__((amdgpu_waves_per_eu(2, 2)))
void vq_kernel(
    const float* __restrict__ ze, const float* __restrict__ emb,
    const unsigned short* __restrict__ ebf,
    float* __restrict__ out_zq, float* __restrict__ out_idxf,
    float* __restrict__ loss, int* __restrict__ done,
    float* __restrict__ out_loss)
{
    extern __shared__ char smem[];
    unsigned short* ebf_l   = (unsigned short*)(smem + L_EBF);
    float*          marg_l  = (float*)(smem + L_MARG);
    int*            ccnt    = (int*)(smem + L_CCNT);
    int*            kch     = (int*)(smem + L_KCH);
    float*          rowmax2 = (float*)(smem + L_ROWMAX);
    int*            cslot   = (int*)(smem + L_CSLOT);

    const int t = threadIdx.x;
    const int n0 = blockIdx.x * 256;
    const int gbase = (n0 >> 12) * 262144 + (n0 & 4095);

    // ---- stage (split roles): t<256 margins; t>=256 codebook -> LDS ----
    if (t < 256) {
        const float* zp = ze + gbase + t;
        float S = 0.0f;
        #pragma unroll
        for (int l = 0; l < 64; ++l) S += fabsf(zp[l * 4096]);
        marg_l[t] = 1.67e-5f * S + 2.0e-4f;   // R5/R6-proven filter margin
        ccnt[t] = 0;
    } else {
        const int tt = t - 256;
        const bf16x8* src = (const bf16x8*)ebf;
        bf16x8* dst = (bf16x8*)ebf_l;
        #pragma unroll 8
        for (int i = 0; i < 32; ++i) dst[tt + i * 256] = src[tt + i * 256];
    }

    // ---- A-fragments straight from global ze (L2-hot): A[m=lane&15][k=q*8+j] ----
    const int wv = t >> 6, lane = t & 63;
    const int r = lane & 15, q = lane >> 4;
    const int pg = wv & 3, kh = wv >> 2;
    const int wp = pg * 64;
    bf16x8 a0[4], a1[4];
    #pragma unroll
    for (int rg = 0; rg < 4; ++rg) {
        const float* zb = ze + gbase + wp + rg * 16 + r;
        #pragma unroll
        for (int j = 0; j < 8; ++j) {
            a0[rg][j] = (short)f2bf(zb[(q * 8 + j) * 4096]);
            a1[rg][j] = (short)f2bf(zb[(32 + q * 8 + j) * 4096]);
        }
    }
    __syncthreads();

    const unsigned short* bptr = ebf_l + (kh * 32) * 1024 + q * 128 + r * 8;

    // ---- pass 1: per-row max of c = z.e over this wave's 512 codes ----
    float rm[16];
    #pragma unroll
    for (int i = 0; i < 16; ++i) rm[i] = -1e30f;
    {
        bf16x8 pb0[2], pb1[2];
        pb0[0] = *(const bf16x8*)(bptr);
        pb1[0] = *(const bf16x8*)(bptr + 512);
        pb0[1] = *(const bf16x8*)(bptr + 1024);
        pb1[1] = *(const bf16x8*)(bptr + 1536);
        #pragma unroll 4
        for (int tile = 0; tile < 32; ++tile) {
            bf16x8 b0 = pb0[tile & 1], b1 = pb1[tile & 1];
            int nt = tile + 2; if (nt > 31) nt = 31;
            pb0[tile & 1] = *(const bf16x8*)(bptr + nt * 1024);
            pb1[tile & 1] = *(const bf16x8*)(bptr + nt * 1024 + 512);
            #pragma unroll
            for (int rg = 0; rg < 4; ++rg) {
                f32x4 c = {0.f, 0.f, 0.f, 0.f};
                c = __builtin_amdgcn_mfma_f32_16x16x32_bf16(a0[rg], b0, c, 0, 0, 0);
                c = __builtin_amdgcn_mfma_f32_16x16x32_bf16(a1[rg], b1, c, 0, 0, 0);
                #pragma unroll
                for (int i = 0; i < 4; ++i)
                    rm[rg * 4 + i] = fmaxf(rm[rg * 4 + i], c[i]);
            }
        }
    }
    // reduce over the 16 code-lanes, publish per-K-half rowmax
    #pragma unroll
    for (int j = 0; j < 16; ++j) {
        float v = rm[j];
        v = fmaxf(v, __shfl_xor(v, 1, 16));
        v = fmaxf(v, __shfl_xor(v, 2, 16));
        v = fmaxf(v, __shfl_xor(v, 4, 16));
        v = fmaxf(v, __shfl_xor(v, 8, 16));
        int row = wp + (j >> 2) * 16 + q * 4 + (j & 3);
        if (r == 0) rowmax2[row * 2 + kh] = v;
    }
    __syncthreads();

    // merged threshold: candidate iff c >= maxc - marg/2
    float thr[16];
    #pragma unroll
    for (int j = 0; j < 16; ++j) {
        int row = wp + (j >> 2) * 16 + q * 4 + (j & 3);
        thr[j] = fmaxf(rowmax2[row * 2], rowmax2[row * 2 + 1]) - 0.5f * marg_l[row];
    }

    // ---- pass 2: collect candidates ----
    {
        bf16x8 pb0[2], pb1[2];
        pb0[0] = *(const bf16x8*)(bptr);
        pb1[0] = *(const bf16x8*)(bptr + 512);
        pb0[1] = *(const bf16x8*)(bptr + 1024);
        pb1[1] = *(const bf16x8*)(bptr + 1536);
        #pragma unroll 4
        for (int tile = 0; tile < 32; ++tile) {
            bf16x8 b0 = pb0[tile & 1], b1 = pb1[tile & 1];
            int nt = tile + 2; if (nt > 31) nt = 31;
            pb0[tile & 1] = *(const bf16x8*)(bptr + nt * 1024);
            pb1[tile & 1] = *(const bf16x8*)(bptr + nt * 1024 + 512);
            int code = kh * 512 + tile * 16 + r;
            #pragma unroll
            for (int rg = 0; rg < 4; ++rg) {
                f32x4 c = {0.f, 0.f, 0.f, 0.f};
                c = __builtin_amdgcn_mfma_f32_16x16x32_bf16(a0[rg], b0, c, 0, 0, 0);
                c = __builtin_amdgcn_mfma_f32_16x16x32_bf16(a1[rg], b1, c, 0, 0, 0);
                #pragma unroll
                for (int i = 0; i < 4; ++i) {
                    if (c[i] >= thr[rg * 4 + i]) {
                        int pp = wp + rg * 16 + q * 4 + i;
                        int ci = atomicAdd(&ccnt[pp], 1);
                        if (ci < CAP) cslot[pp * CAP + ci] = code;
                    }
                }
            }
        }
    }
    __syncthreads();

    // ---- exact fp32 numpy rescore + lex-(score,k) select (owner t<256) ----
    if (t < 256) {
        float z[64];
        const float* zp = ze + gbase + t;
        #pragma unroll
        for (int l = 0; l < 64; ++l) z[l] = zp[l * 4096];   // L2/L3-hot reload
        float znorm = np_pairwise_sumsq64(z);
        int cnt = ccnt[t]; if (cnt > CAP) cnt = CAP;
        float best = 1e30f; int bk = 1 << 20;
        for (int c = 0; c < cnt; ++c) {
            int k = cslot[t * CAP + c];
            float e[64];
            const float4* er = (const float4*)(emb + k * 64);
            #pragma unroll
            for (int j = 0; j < 16; ++j) {
                float4 v = er[j];
                e[4*j] = v.x; e[4*j+1] = v.y; e[4*j+2] = v.z; e[4*j+3] = v.w;
            }
            float en = np_pairwise_sumsq64(e);          // bit-exact numpy enorm
            float acc = 0.0f;
            #pragma unroll
            for (int l = 0; l < 64; ++l) acc = fmaf(z[l], e[l], acc);  // sgemm order
            float sc = __fsub_rn(__fadd_rn(znorm, en), __fmul_rn(2.0f, acc));
            if (sc < best || (sc == best && k < bk)) { best = sc; bk = k; }
        }
        kch[t] = bk;
        out_idxf[n0 + t] = (float)bk;
    }
    __syncthreads();

    // ---- epilogue: all 512 threads, dims split (h = t>>8) ----
    {
        const int p = t & 255, h = t >> 8;
        const int bk = kch[p];
        const float* er = emb + bk * 64 + h * 32;
        const float* zp = ze + gbase + p + (h * 32) * 4096;
        float* op = out_zq + gbase + p + (h * 32) * 4096;
        float ls = 0.0f;
        #pragma unroll
        for (int j = 0; j < 32; ++j) {
            float qv = er[j];
            float zv = zp[j * 4096];
            op[j * 4096] = qv;
            float d = qv - zv;
            ls = fmaf(d, d, ls);
        }
        #pragma unroll
        for (int off = 32; off > 0; off >>= 1) ls += __shfl_down(ls, off, 64);
        if (lane == 0) atomicAdd(loss, ls);
    }

    // ---- last block finalizes loss (device-scope atomics) ----
    __syncthreads();
    if (t == 0) {
        __threadfence();
        int old = atomicAdd(done, 1);
        if (old == (int)gridDim.x - 1) {
            __threadfence();
            float total = atomicAdd(loss, 0.0f);   // coherent read
            *out_loss = 1.25f * total / 4194304.0f;
        }
    }
}

extern "C" void kernel_launch(void* const* d_in, const int* in_sizes, int n_in,
                              void* d_out, int out_size, void* d_ws, size_t ws_size,
                              hipStream_t stream)
{
    const float* ze  = (const float*)d_in[0];   // (16,64,64,64) fp32
    const float* emb = (const float*)d_in[1];   // (1024,64) fp32
    float* out = (float*)d_out;
    float* out_zq   = out;                 // 4194304
    float* out_loss = out + 4194304;       // 1
    float* out_idxf = out + 4194305;       // 65536

    char* w = (char*)d_ws;
    float*          ws_loss = (float*)(w + WS_LOSS);
    int*            ws_done = (int*)(w + WS_DONE);
    unsigned short* ebf     = (unsigned short*)(w + WS_EBF);

    // allow >64KB dynamic LDS (no-op if already permitted)
    static bool attr_set = false;
    if (!attr_set) {
        hipFuncSetAttribute((const void*)vq_kernel,
                            hipFuncAttributeMaxDynamicSharedMemorySize, L_TOTAL);
        attr_set = true;
    }

    prep_kernel<<<4, 256, 0, stream>>>(emb, ebf, ws_loss, ws_done);
    vq_kernel<<<256, 512, L_TOTAL, stream>>>(ze, emb, ebf, out_zq, out_idxf,
                                             ws_loss, ws_done, out_loss);
}